// Round 1
// baseline (12578.954 us; speedup 1.0000x reference)
//
#include <hip/hip_runtime.h>
#include <math.h>

#define STEPS 256
#define BATCH 128
#define INSZ  512
#define H1SZ  1536
#define H2SZ  1536
#define NOUT  512
#define K1    2048   // INSZ + H1SZ
#define K2    3072   // H1SZ + H2SZ
#define NBLK  256

typedef short bf16x8 __attribute__((ext_vector_type(8)));
typedef float f32x4  __attribute__((ext_vector_type(4)));
typedef unsigned short u16;

__device__ __forceinline__ u16 f2bf(float f) {
  unsigned u = __builtin_bit_cast(unsigned, f);
  u += 0x7fffu + ((u >> 16) & 1u);          // round-to-nearest-even
  return (u16)(u >> 16);
}

__device__ __forceinline__ f32x4 mfma16(bf16x8 a, bf16x8 b, f32x4 c) {
  return __builtin_amdgcn_mfma_f32_16x16x32_bf16(a, b, c, 0, 0, 0);
}

__device__ __forceinline__ bf16x8 cvt8(const float* p) {
  f32x4 lo = *(const f32x4*)p;
  f32x4 hi = *(const f32x4*)(p + 4);
  bf16x8 r;
  r[0] = (short)f2bf(lo[0]); r[1] = (short)f2bf(lo[1]);
  r[2] = (short)f2bf(lo[2]); r[3] = (short)f2bf(lo[3]);
  r[4] = (short)f2bf(hi[0]); r[5] = (short)f2bf(hi[1]);
  r[6] = (short)f2bf(hi[2]); r[7] = (short)f2bf(hi[3]);
  return r;
}

// ---- grid barrier: sense-free generation barrier, agent scope ----
__device__ __forceinline__ void grid_barrier(int* arrive, int* release) {
  __syncthreads();                       // compiler drains vmcnt before s_barrier
  if (threadIdx.x == 0) {
    int gen = __hip_atomic_load(release, __ATOMIC_RELAXED, __HIP_MEMORY_SCOPE_AGENT);
    int old = __hip_atomic_fetch_add(arrive, 1, __ATOMIC_ACQ_REL, __HIP_MEMORY_SCOPE_AGENT);
    if (old == (int)gridDim.x - 1) {
      __hip_atomic_store(arrive, 0, __ATOMIC_RELAXED, __HIP_MEMORY_SCOPE_AGENT);
      __hip_atomic_fetch_add(release, 1, __ATOMIC_RELEASE, __HIP_MEMORY_SCOPE_AGENT);
    } else {
      while (__hip_atomic_load(release, __ATOMIC_RELAXED, __HIP_MEMORY_SCOPE_AGENT) == gen) {
        __builtin_amdgcn_s_sleep(1);
      }
    }
    (void)__hip_atomic_load(release, __ATOMIC_ACQUIRE, __HIP_MEMORY_SCOPE_AGENT); // buffer_inv
  }
  __syncthreads();
}

// generic bf16 K-loop: wave computes 32x32 tile (2x2 frags) over klen
__device__ __forceinline__ void kloop_bf16(const u16* __restrict__ ar0, const u16* __restrict__ ar1,
                                           const u16* __restrict__ br0, const u16* __restrict__ br1,
                                           int klen, f32x4 acc[2][2]) {
#pragma unroll 4
  for (int k = 0; k < klen; k += 32) {
    bf16x8 a0 = *(const bf16x8*)(ar0 + k);
    bf16x8 a1 = *(const bf16x8*)(ar1 + k);
    bf16x8 b0 = *(const bf16x8*)(br0 + k);
    bf16x8 b1 = *(const bf16x8*)(br1 + k);
    acc[0][0] = mfma16(a0, b0, acc[0][0]);
    acc[0][1] = mfma16(a0, b1, acc[0][1]);
    acc[1][0] = mfma16(a1, b0, acc[1][0]);
    acc[1][1] = mfma16(a1, b1, acc[1][1]);
  }
}

__device__ __forceinline__ void store_red(float (*red)[32][33], int w, int kg, int r16,
                                          f32x4 acc[2][2]) {
#pragma unroll
  for (int mi = 0; mi < 2; ++mi)
#pragma unroll
    for (int ni = 0; ni < 2; ++ni)
#pragma unroll
      for (int r = 0; r < 4; ++r)
        red[w][mi * 16 + kg * 4 + r][ni * 16 + r16] = acc[mi][ni][r];
}

// GEMM3: out tile = h2src[128,1536] @ WoT + bo (fp32 store, no tanh)
__device__ __forceinline__ void gemm3_tile(const u16* __restrict__ h2src, float* __restrict__ op,
                                           const u16* __restrict__ WoT, const float* __restrict__ bo,
                                           int m0, int n0, int w, int kg, int r16, int tid,
                                           float (*red)[32][33]) {
  f32x4 acc[2][2] = {};
  const u16* B0 = WoT + (size_t)(n0 + r16) * H2SZ + w * 384 + kg * 8;
  const u16* B1 = B0 + 16 * H2SZ;
  const u16* A0 = h2src + (size_t)(m0 + r16) * H2SZ + w * 384 + kg * 8;
  const u16* A1 = A0 + 16 * H2SZ;
  kloop_bf16(A0, A1, B0, B1, 384, acc);
  store_red(red, w, kg, r16, acc);
  __syncthreads();
#pragma unroll
  for (int e = tid; e < 1024; e += 256) {
    int rr = e >> 5, rc = e & 31;
    float s = red[0][rr][rc] + red[1][rr][rc] + red[2][rr][rc] + red[3][rr][rc] + bo[n0 + rc];
    op[(size_t)(m0 + rr) * NOUT + n0 + rc] = s;
  }
}

__global__ __launch_bounds__(256, 2) void rnn_main(
    const float* __restrict__ x,
    const u16* __restrict__ W1T, const u16* __restrict__ W2T, const u16* __restrict__ WoT,
    const float* __restrict__ b1, const float* __restrict__ b2, const float* __restrict__ bo,
    u16* __restrict__ h1b, u16* __restrict__ h2b,
    float* __restrict__ out, int* __restrict__ bar)
{
  __shared__ float red[4][32][33];
  const int tid = threadIdx.x;
  const int w = tid >> 6, lane = tid & 63;
  const int r16 = lane & 15, kg = lane >> 4;
  const int bid = blockIdx.x;
  int* arrive  = bar;
  int* release = bar + 32;

  const int jm = (bid < 192) ? bid / 48 : (bid - 192) / 16;
  const int jn = (bid < 192) ? bid % 48 : (bid - 192) % 16;
  const int m0 = jm * 32;
  const int n0 = jn * 32;

  for (int t = 0; t < STEPS; ++t) {
    const u16* h1p = h1b + (size_t)(t & 1) * (BATCH * H1SZ);
    u16*       h1c = h1b + (size_t)((t & 1) ^ 1) * (BATCH * H1SZ);
    const u16* h2p = h2b + (size_t)(t & 1) * (BATCH * H2SZ);
    u16*       h2c = h2b + (size_t)((t & 1) ^ 1) * (BATCH * H2SZ);

    // ---------------- phase A: h1_t = tanh([x_t | h1_prev] @ W1 + b1);  out[t] = h2_prev @ Wo + bo
    if (bid < 192) {
      f32x4 acc[2][2] = {};
      const u16* B0 = W1T + (size_t)(n0 + r16) * K1 + w * 512 + kg * 8;
      const u16* B1 = B0 + 16 * K1;
      if (w == 0) {
        // K slice [0,512): input x_t, fp32 -> bf16 on the fly
        const float* xr0 = x + ((size_t)t * BATCH + m0 + r16) * INSZ + kg * 8;
        const float* xr1 = xr0 + 16 * INSZ;
#pragma unroll 2
        for (int k = 0; k < 512; k += 32) {
          bf16x8 a0 = cvt8(xr0 + k);
          bf16x8 a1 = cvt8(xr1 + k);
          bf16x8 b0 = *(const bf16x8*)(B0 + k);
          bf16x8 b1 = *(const bf16x8*)(B1 + k);
          acc[0][0] = mfma16(a0, b0, acc[0][0]);
          acc[0][1] = mfma16(a0, b1, acc[0][1]);
          acc[1][0] = mfma16(a1, b0, acc[1][0]);
          acc[1][1] = mfma16(a1, b1, acc[1][1]);
        }
      } else {
        // K slice [w*512,(w+1)*512): h1_prev
        const u16* A0 = h1p + (size_t)(m0 + r16) * H1SZ + (w * 512 - 512) + kg * 8;
        const u16* A1 = A0 + 16 * H1SZ;
        kloop_bf16(A0, A1, B0, B1, 512, acc);
      }
      store_red(red, w, kg, r16, acc);
      __syncthreads();
#pragma unroll
      for (int e = tid; e < 1024; e += 256) {
        int rr = e >> 5, rc = e & 31;
        float s = red[0][rr][rc] + red[1][rr][rc] + red[2][rr][rc] + red[3][rr][rc] + b1[n0 + rc];
        h1c[(size_t)(m0 + rr) * H1SZ + n0 + rc] = f2bf(tanhf(s));
      }
    } else if (t > 0) {
      gemm3_tile(h2p, out + (size_t)t * (BATCH * NOUT), WoT, bo, m0, n0, w, kg, r16, tid, red);
    }
    grid_barrier(arrive, release);

    // ---------------- phase B: h2_t = tanh([h1_t | h2_prev] @ W2 + b2)
    if (bid < 192) {
      f32x4 acc[2][2] = {};
      const u16* B0 = W2T + (size_t)(n0 + r16) * K2 + w * 768 + kg * 8;
      const u16* B1 = B0 + 16 * K2;
      const u16* A  = (w < 2) ? h1c : h2p;
      const int  ab = (w < 2) ? w * 768 : w * 768 - 1536;
      const u16* A0 = A + (size_t)(m0 + r16) * H1SZ + ab + kg * 8;
      const u16* A1 = A0 + 16 * H1SZ;
      kloop_bf16(A0, A1, B0, B1, 768, acc);
      store_red(red, w, kg, r16, acc);
      __syncthreads();
#pragma unroll
      for (int e = tid; e < 1024; e += 256) {
        int rr = e >> 5, rc = e & 31;
        float s = red[0][rr][rc] + red[1][rr][rc] + red[2][rr][rc] + red[3][rr][rc] + b2[n0 + rc];
        h2c[(size_t)(m0 + rr) * H2SZ + n0 + rc] = f2bf(tanhf(s));
      }
    }
    grid_barrier(arrive, release);
  }

  // epilogue: out[256] = h2_255 @ Wo + bo   (h2_255 lives in buffer 0 after t=255)
  if (bid >= 192) {
    gemm3_tile(h2b, out + (size_t)STEPS * (BATCH * NOUT), WoT, bo, m0, n0, w, kg, r16, tid, red);
  }
}

// LDS-tiled transpose + fp32->bf16:  dst[n*K + k] = bf16(src[k*N + n])
__global__ void transpose_cvt(const float* __restrict__ src, u16* __restrict__ dst, int K, int N) {
  __shared__ u16 tile[32][33];
  int kb = blockIdx.x * 32, nb = blockIdx.y * 32;
  int tx = threadIdx.x & 31, ty = threadIdx.x >> 5;   // 32 x 8
  for (int i = ty; i < 32; i += 8)
    tile[i][tx] = f2bf(src[(size_t)(kb + i) * N + nb + tx]);
  __syncthreads();
  for (int i = ty; i < 32; i += 8)
    dst[(size_t)(nb + i) * K + kb + tx] = tile[tx][i];
}

extern "C" void kernel_launch(void* const* d_in, const int* in_sizes, int n_in,
                              void* d_out, int out_size, void* d_ws, size_t ws_size,
                              hipStream_t stream) {
  const float* x  = (const float*)d_in[0];
  const float* W1 = (const float*)d_in[1];
  const float* b1 = (const float*)d_in[2];
  const float* W2 = (const float*)d_in[3];
  const float* b2 = (const float*)d_in[4];
  const float* Wo = (const float*)d_in[5];
  const float* bo = (const float*)d_in[6];
  float* out = (float*)d_out;
  char*  ws  = (char*)d_ws;

  // ws layout (bytes)
  u16* W1T = (u16*)(ws);                    // 1536*2048*2 = 6291456
  u16* W2T = (u16*)(ws + 6291456);          // 1536*3072*2 = 9437184
  u16* WoT = (u16*)(ws + 15728640);         //  512*1536*2 = 1572864
  u16* h1b = (u16*)(ws + 17301504);         // 2*128*1536*2 = 786432
  u16* h2b = (u16*)(ws + 18087936);         // 786432
  int* bar = (int*)(ws + 18874368);         // barrier state (arrive @+0, release @+128B)

  // zero h-state + barrier state (every call: deterministic), zero out[0]
  hipMemsetAsync(ws + 17301504, 0, 786432 * 2 + 256, stream);
  hipMemsetAsync(d_out, 0, (size_t)BATCH * NOUT * sizeof(float), stream);

  transpose_cvt<<<dim3(K1 / 32, H1SZ / 32), 256, 0, stream>>>(W1, W1T, K1, H1SZ);
  transpose_cvt<<<dim3(K2 / 32, H1SZ / 32), 256, 0, stream>>>(W2, W2T, K2, H1SZ);
  transpose_cvt<<<dim3(H2SZ / 32, NOUT / 32), 256, 0, stream>>>(Wo, WoT, H2SZ, NOUT);

  rnn_main<<<NBLK, 256, 0, stream>>>(x, W1T, W2T, WoT, b1, b2, bo, h1b, h2b, out, bar);
}

// Round 2
// 10750.049 us; speedup vs baseline: 1.1701x; 1.1701x over previous
//
#include <hip/hip_runtime.h>
#include <math.h>

#define STEPS 256
#define BATCH 128
#define INSZ  512
#define H1SZ  1536
#define H2SZ  1536
#define NOUT  512
#define K1    2048   // INSZ + H1SZ
#define K2    3072   // H1SZ + H2SZ
#define NB_G1 48
#define NB_G2 48
#define NB_G3 16
#define NBLK  112
#define NPHASE 258   // pipelined: G1 k in [0,255], G2 in [1,256], G3 in [2,257]

typedef short bf16x8 __attribute__((ext_vector_type(8)));
typedef float f32x4  __attribute__((ext_vector_type(4)));
typedef unsigned short u16;

__device__ __forceinline__ u16 f2bf(float f) {
  unsigned u = __builtin_bit_cast(unsigned, f);
  u += 0x7fffu + ((u >> 16) & 1u);          // round-to-nearest-even
  return (u16)(u >> 16);
}

__device__ __forceinline__ f32x4 mfma16(bf16x8 a, bf16x8 b, f32x4 c) {
  return __builtin_amdgcn_mfma_f32_16x16x32_bf16(a, b, c, 0, 0, 0);
}

// 8 fp32 -> bf16x8 via packed cvt (RTNE), 4 VALU ops
__device__ __forceinline__ bf16x8 cvt8(const float* p) {
  f32x4 lo = *(const f32x4*)p;
  f32x4 hi = *(const f32x4*)(p + 4);
  union { unsigned u[4]; bf16x8 v; } r;
  asm("v_cvt_pk_bf16_f32 %0, %1, %2" : "=v"(r.u[0]) : "v"(lo[0]), "v"(lo[1]));
  asm("v_cvt_pk_bf16_f32 %0, %1, %2" : "=v"(r.u[1]) : "v"(lo[2]), "v"(lo[3]));
  asm("v_cvt_pk_bf16_f32 %0, %1, %2" : "=v"(r.u[2]) : "v"(hi[0]), "v"(hi[1]));
  asm("v_cvt_pk_bf16_f32 %0, %1, %2" : "=v"(r.u[3]) : "v"(hi[2]), "v"(hi[3]));
  return r.v;
}

// ---- flag-tree grid barrier: parallel arrival stores, block0 scans, single release ----
// bar[i*16] = per-block flag (64B apart); bar[NBLK*16] = release word.
__device__ __forceinline__ void grid_barrier(int* bar, int target) {
  __syncthreads();   // all waves' prior stores drained (compiler emits vmcnt(0))
  const int tid = threadIdx.x;
  if (blockIdx.x == 0) {
    if (tid == 0)
      __hip_atomic_store(&bar[0], target, __ATOMIC_RELEASE, __HIP_MEMORY_SCOPE_AGENT);
    if (tid < NBLK) {
      while (__hip_atomic_load(&bar[tid * 16], __ATOMIC_RELAXED, __HIP_MEMORY_SCOPE_AGENT) < target)
        __builtin_amdgcn_s_sleep(1);
    }
    __syncthreads();  // all flags observed
    if (tid == 0) {
      (void)__hip_atomic_load(&bar[0], __ATOMIC_ACQUIRE, __HIP_MEMORY_SCOPE_AGENT);  // inv caches
      __hip_atomic_store(&bar[NBLK * 16], target, __ATOMIC_RELEASE, __HIP_MEMORY_SCOPE_AGENT);
    }
    __syncthreads();
  } else {
    if (tid == 0) {
      __hip_atomic_store(&bar[blockIdx.x * 16], target, __ATOMIC_RELEASE, __HIP_MEMORY_SCOPE_AGENT);
      while (__hip_atomic_load(&bar[NBLK * 16], __ATOMIC_RELAXED, __HIP_MEMORY_SCOPE_AGENT) < target)
        __builtin_amdgcn_s_sleep(1);
      (void)__hip_atomic_load(&bar[NBLK * 16], __ATOMIC_ACQUIRE, __HIP_MEMORY_SCOPE_AGENT);
    }
    __syncthreads();
  }
}

__device__ __forceinline__ void store_red8(float (*red)[128][32], int kw, int kg, int r16,
                                           const f32x4 acc[8][2]) {
#pragma unroll
  for (int mf = 0; mf < 8; ++mf)
#pragma unroll
    for (int nf = 0; nf < 2; ++nf)
#pragma unroll
      for (int r = 0; r < 4; ++r)
        red[kw][mf * 16 + kg * 4 + r][nf * 16 + r16] = acc[mf][nf][r];
}

template<int LDD>
__device__ __forceinline__ void reduce_tanh_store(float (*red)[128][32], const float* __restrict__ bias,
                                                  u16* __restrict__ dst, int n0, int tid) {
#pragma unroll
  for (int i = 0; i < 16; ++i) {
    int e = i * 256 + tid;
    int rr = e >> 5, rc = e & 31;
    float s = red[0][rr][rc] + red[1][rr][rc] + red[2][rr][rc] + red[3][rr][rc] + bias[n0 + rc];
    dst[(size_t)rr * LDD + n0 + rc] = f2bf(tanhf(s));
  }
}

__global__ __launch_bounds__(256, 1) void rnn_main(
    const float* __restrict__ x,
    const u16* __restrict__ W1T, const u16* __restrict__ W2T, const u16* __restrict__ WoT,
    const float* __restrict__ b1, const float* __restrict__ b2, const float* __restrict__ bo,
    u16* __restrict__ h1b, u16* __restrict__ h2b,
    float* __restrict__ out, int* __restrict__ bar)
{
  __shared__ float red[4][128][32];       // 64 KB: K-split reduction buffer
  const int tid = threadIdx.x;
  const int kw = tid >> 6, lane = tid & 63;
  const int r16 = lane & 15, kg = lane >> 4;
  const int bid = blockIdx.x;

  if (bid < NB_G1) {
    // ---------- GEMM1 blocks: h1[k] = tanh([x_k | h1[k-1]] @ W1 + b1), 32 cols each
    const int n0 = bid * 32;
    // wave kw K-slice: x cols [kw*128,+128) then h1 cols [kw*384,+384)
    bf16x8 Br[16][2];
#pragma unroll
    for (int ks = 0; ks < 16; ++ks) {
      int kofs = (ks < 4) ? (kw * 128 + ks * 32 + kg * 8)
                          : (512 + kw * 384 + (ks - 4) * 32 + kg * 8);
#pragma unroll
      for (int nf = 0; nf < 2; ++nf)
        Br[ks][nf] = *(const bf16x8*)(W1T + (size_t)(n0 + nf * 16 + r16) * K1 + kofs);
    }
    for (int k = 0; k < NPHASE; ++k) {
      if (k < STEPS) {
        const u16* h1p = h1b + (size_t)((k + 1) & 1) * (BATCH * H1SZ);  // h1[k-1]
        u16*       h1c = h1b + (size_t)(k & 1) * (BATCH * H1SZ);        // h1[k]
        f32x4 acc[8][2] = {};
        const float* xr = x + (size_t)k * BATCH * INSZ + kw * 128 + kg * 8;
        const u16*   ar = h1p + kw * 384 + kg * 8;
#pragma unroll
        for (int ks = 0; ks < 4; ++ks)
#pragma unroll
          for (int mf = 0; mf < 8; ++mf) {
            bf16x8 a = cvt8(xr + (size_t)(mf * 16 + r16) * INSZ + ks * 32);
            acc[mf][0] = mfma16(a, Br[ks][0], acc[mf][0]);
            acc[mf][1] = mfma16(a, Br[ks][1], acc[mf][1]);
          }
#pragma unroll
        for (int ks = 4; ks < 16; ++ks)
#pragma unroll
          for (int mf = 0; mf < 8; ++mf) {
            bf16x8 a = *(const bf16x8*)(ar + (size_t)(mf * 16 + r16) * H1SZ + (ks - 4) * 32);
            acc[mf][0] = mfma16(a, Br[ks][0], acc[mf][0]);
            acc[mf][1] = mfma16(a, Br[ks][1], acc[mf][1]);
          }
        store_red8(red, kw, kg, r16, acc);
        __syncthreads();
        reduce_tanh_store<H1SZ>(red, b1, h1c, n0, tid);
      }
      if (k < NPHASE - 1) grid_barrier(bar, k + 1);
    }
  } else if (bid < NB_G1 + NB_G2) {
    // ---------- GEMM2 blocks: h2[k-1] = tanh([h1[k-1] | h2[k-2]] @ W2 + b2)
    const int n0 = (bid - NB_G1) * 32;
    bf16x8 Br[24][2];
#pragma unroll
    for (int ks = 0; ks < 24; ++ks)
#pragma unroll
      for (int nf = 0; nf < 2; ++nf)
        Br[ks][nf] = *(const bf16x8*)(W2T + (size_t)(n0 + nf * 16 + r16) * K2
                                      + kw * 768 + ks * 32 + kg * 8);
    for (int k = 0; k < NPHASE; ++k) {
      if (k >= 1 && k <= STEPS) {
        const u16* h1r = h1b + (size_t)((k + 1) & 1) * (BATCH * H1SZ);  // h1[k-1]
        const u16* h2r = h2b + (size_t)(k & 1) * (BATCH * H2SZ);        // h2[k-2]
        u16*       h2c = h2b + (size_t)((k + 1) & 1) * (BATCH * H2SZ);  // h2[k-1]
        const u16* A  = (kw < 2) ? h1r : h2r;
        const u16* ar = A + (kw & 1) * 768 + kg * 8;
        f32x4 acc[8][2] = {};
#pragma unroll
        for (int ks = 0; ks < 24; ++ks)
#pragma unroll
          for (int mf = 0; mf < 8; ++mf) {
            bf16x8 a = *(const bf16x8*)(ar + (size_t)(mf * 16 + r16) * H1SZ + ks * 32);
            acc[mf][0] = mfma16(a, Br[ks][0], acc[mf][0]);
            acc[mf][1] = mfma16(a, Br[ks][1], acc[mf][1]);
          }
        store_red8(red, kw, kg, r16, acc);
        __syncthreads();
        reduce_tanh_store<H2SZ>(red, b2, h2c, n0, tid);
      }
      if (k < NPHASE - 1) grid_barrier(bar, k + 1);
    }
  } else {
    // ---------- GEMM3 blocks: out[k-2] = h2[k-2] @ Wo + bo  -> d_out row (k-1)
    const int n0 = (bid - NB_G1 - NB_G2) * 32;
    bf16x8 Br[12][2];
#pragma unroll
    for (int ks = 0; ks < 12; ++ks)
#pragma unroll
      for (int nf = 0; nf < 2; ++nf)
        Br[ks][nf] = *(const bf16x8*)(WoT + (size_t)(n0 + nf * 16 + r16) * H2SZ
                                      + kw * 384 + ks * 32 + kg * 8);
    for (int k = 0; k < NPHASE; ++k) {
      if (k >= 2) {
        const u16* h2r = h2b + (size_t)(k & 1) * (BATCH * H2SZ);        // h2[k-2]
        float*     op  = out + (size_t)(k - 1) * BATCH * NOUT;
        const u16* ar  = h2r + kw * 384 + kg * 8;
        f32x4 acc[8][2] = {};
#pragma unroll
        for (int ks = 0; ks < 12; ++ks)
#pragma unroll
          for (int mf = 0; mf < 8; ++mf) {
            bf16x8 a = *(const bf16x8*)(ar + (size_t)(mf * 16 + r16) * H2SZ + ks * 32);
            acc[mf][0] = mfma16(a, Br[ks][0], acc[mf][0]);
            acc[mf][1] = mfma16(a, Br[ks][1], acc[mf][1]);
          }
        store_red8(red, kw, kg, r16, acc);
        __syncthreads();
#pragma unroll
        for (int i = 0; i < 16; ++i) {
          int e = i * 256 + tid;
          int rr = e >> 5, rc = e & 31;
          float s = red[0][rr][rc] + red[1][rr][rc] + red[2][rr][rc] + red[3][rr][rc] + bo[n0 + rc];
          op[(size_t)rr * NOUT + n0 + rc] = s;
        }
      }
      if (k < NPHASE - 1) grid_barrier(bar, k + 1);
    }
  }
}

// LDS-tiled transpose + fp32->bf16:  dst[n*K + k] = bf16(src[k*N + n])
__global__ void transpose_cvt(const float* __restrict__ src, u16* __restrict__ dst, int K, int N) {
  __shared__ u16 tile[32][33];
  int kb = blockIdx.x * 32, nb = blockIdx.y * 32;
  int tx = threadIdx.x & 31, ty = threadIdx.x >> 5;   // 32 x 8
  for (int i = ty; i < 32; i += 8)
    tile[i][tx] = f2bf(src[(size_t)(kb + i) * N + nb + tx]);
  __syncthreads();
  for (int i = ty; i < 32; i += 8)
    dst[(size_t)(nb + i) * K + kb + tx] = tile[tx][i];
}

extern "C" void kernel_launch(void* const* d_in, const int* in_sizes, int n_in,
                              void* d_out, int out_size, void* d_ws, size_t ws_size,
                              hipStream_t stream) {
  const float* x  = (const float*)d_in[0];
  const float* W1 = (const float*)d_in[1];
  const float* b1 = (const float*)d_in[2];
  const float* W2 = (const float*)d_in[3];
  const float* b2 = (const float*)d_in[4];
  const float* Wo = (const float*)d_in[5];
  const float* bo = (const float*)d_in[6];
  float* out = (float*)d_out;
  char*  ws  = (char*)d_ws;

  // ws layout (bytes)
  u16* W1T = (u16*)(ws);                    // 1536*2048*2 = 6291456
  u16* W2T = (u16*)(ws + 6291456);          // 1536*3072*2 = 9437184
  u16* WoT = (u16*)(ws + 15728640);         //  512*1536*2 = 1572864
  u16* h1b = (u16*)(ws + 17301504);         // 2*128*1536*2 = 786432
  u16* h2b = (u16*)(ws + 18087936);         // 786432
  int* bar = (int*)(ws + 18874368);         // flags[112*16] + release

  // zero h-state + barrier flags (every call: deterministic); zero out row 0 (delay)
  hipMemsetAsync(ws + 17301504, 0, 786432 * 2 + 8192, stream);
  hipMemsetAsync(d_out, 0, (size_t)BATCH * NOUT * sizeof(float), stream);

  transpose_cvt<<<dim3(K1 / 32, H1SZ / 32), 256, 0, stream>>>(W1, W1T, K1, H1SZ);
  transpose_cvt<<<dim3(K2 / 32, H1SZ / 32), 256, 0, stream>>>(W2, W2T, K2, H1SZ);
  transpose_cvt<<<dim3(H2SZ / 32, NOUT / 32), 256, 0, stream>>>(Wo, WoT, H2SZ, NOUT);

  rnn_main<<<NBLK, 256, 0, stream>>>(x, W1T, W2T, WoT, b1, b2, bo, h1b, h2b, out, bar);
}

// Round 3
// 7229.344 us; speedup vs baseline: 1.7400x; 1.4870x over previous
//
#include <hip/hip_runtime.h>
#include <math.h>

#define STEPS 256
#define BATCH 128
#define INSZ  512
#define H1SZ  1536
#define H2SZ  1536
#define NOUT  512
#define K1    2048   // INSZ + H1SZ
#define K2    3072   // H1SZ + H2SZ
#define NB1   48
#define NB2   48
#define NB3   16
#define NBLK  112
#define RING  4

typedef short bf16x8 __attribute__((ext_vector_type(8)));
typedef float f32x4  __attribute__((ext_vector_type(4)));
typedef unsigned short u16;

__device__ __forceinline__ u16 f2bf(float f) {
  unsigned u = __builtin_bit_cast(unsigned, f);
  u += 0x7fffu + ((u >> 16) & 1u);          // RTNE
  return (u16)(u >> 16);
}

__device__ __forceinline__ f32x4 mfma16(bf16x8 a, bf16x8 b, f32x4 c) {
  return __builtin_amdgcn_mfma_f32_16x16x32_bf16(a, b, c, 0, 0, 0);
}

// 8 fp32 -> bf16x8 via packed cvt (RTNE)
__device__ __forceinline__ bf16x8 cvt8(const float* p) {
  f32x4 lo = *(const f32x4*)p;
  f32x4 hi = *(const f32x4*)(p + 4);
  union { unsigned u[4]; bf16x8 v; } r;
  asm("v_cvt_pk_bf16_f32 %0, %1, %2" : "=v"(r.u[0]) : "v"(lo[0]), "v"(lo[1]));
  asm("v_cvt_pk_bf16_f32 %0, %1, %2" : "=v"(r.u[1]) : "v"(lo[2]), "v"(lo[3]));
  asm("v_cvt_pk_bf16_f32 %0, %1, %2" : "=v"(r.u[2]) : "v"(hi[0]), "v"(hi[1]));
  asm("v_cvt_pk_bf16_f32 %0, %1, %2" : "=v"(r.u[3]) : "v"(hi[2]), "v"(hi[3]));
  return r.v;
}

// ---- system-scope sync primitives (no cache invalidation anywhere) ----
__device__ __forceinline__ int sysload(const int* p) {
  return __hip_atomic_load(p, __ATOMIC_RELAXED, __HIP_MEMORY_SCOPE_SYSTEM);
}
__device__ __forceinline__ void sysstore(int* p, int v) {
  __hip_atomic_store(p, v, __ATOMIC_RELAXED, __HIP_MEMORY_SCOPE_SYSTEM);
}
// release: buffer_wbl2 (writeback, NOT invalidate) + waitcnt + sc0sc1 store
__device__ __forceinline__ void relstore(int* p, int v) {
  __hip_atomic_store(p, v, __ATOMIC_RELEASE, __HIP_MEMORY_SCOPE_SYSTEM);
}
__device__ __forceinline__ void wait_ge(const int* p, int v) {
  while (sysload(p) < v) __builtin_amdgcn_s_sleep(2);
}

// coherent (L1/L2-bypass) 16B load of bf16x8
#define LOAD_SC(dst, ptr) \
  asm volatile("global_load_dwordx4 %0, %1, off sc0 sc1" : "=v"(dst) : "v"(ptr))
#define LOAD_SC_OFS(dst, ptr, ofs) \
  asm volatile("global_load_dwordx4 %0, %1, off offset:%2 sc0 sc1" : "=v"(dst) : "v"(ptr), "i"(ofs))

// K-loop over sc1-bypass A rows, 2-deep pipelined, counted vmcnt.
// rp[mf]: per-lane row pointer (row mf*16+r16, at this wave's K-slice + kg*8).
template<int NKS>
__device__ __forceinline__ void kloop_sc1(const u16* const* rp, const bf16x8 (*Br)[2],
                                          f32x4 (*acc)[2]) {
  bf16x8 A0[8], A1[8];
#pragma unroll
  for (int mf = 0; mf < 8; ++mf) LOAD_SC(A0[mf], rp[mf]);
#pragma unroll
  for (int ks = 0; ks < NKS; ++ks) {
    bf16x8* cur = (ks & 1) ? A1 : A0;
    bf16x8* nxt = (ks & 1) ? A0 : A1;
    if (ks + 1 < NKS) {
#pragma unroll
      for (int mf = 0; mf < 8; ++mf) LOAD_SC_OFS(nxt[mf], rp[mf], (ks + 1) * 64);
      asm volatile("s_waitcnt vmcnt(8)" ::: "memory");
    } else {
      asm volatile("s_waitcnt vmcnt(0)" ::: "memory");
    }
    __builtin_amdgcn_sched_barrier(0);
#pragma unroll
    for (int mf = 0; mf < 8; ++mf) {
      acc[mf][0] = mfma16(cur[mf], Br[ks][0], acc[mf][0]);
      acc[mf][1] = mfma16(cur[mf], Br[ks][1], acc[mf][1]);
    }
  }
}

// x-path: normal cached fp32 loads + cvt (x is read-only -> never stale)
__device__ __forceinline__ void kloop_x(const float* const* xp, const bf16x8 (*Br)[2],
                                        f32x4 (*acc)[2]) {
#pragma unroll
  for (int ks = 0; ks < 8; ++ks)
#pragma unroll
    for (int mf = 0; mf < 8; ++mf) {
      bf16x8 a = cvt8(xp[mf] + ks * 32);
      acc[mf][0] = mfma16(a, Br[ks][0], acc[mf][0]);
      acc[mf][1] = mfma16(a, Br[ks][1], acc[mf][1]);
    }
}

__device__ __forceinline__ void store_red8(float (*red)[128][32], int kw, int kg, int r16,
                                           const f32x4 (*acc)[2]) {
#pragma unroll
  for (int mf = 0; mf < 8; ++mf)
#pragma unroll
    for (int nf = 0; nf < 2; ++nf)
#pragma unroll
      for (int r = 0; r < 4; ++r)
        red[kw][mf * 16 + kg * 4 + r][nf * 16 + r16] = acc[mf][nf][r];
}

__device__ __forceinline__ void reduce_tanh_bf16(const float (*red)[128][32], const float* bias,
                                                 u16* dst, int n0, int tid, int ld) {
#pragma unroll
  for (int i = 0; i < 8; ++i) {
    int e = i * 512 + tid, rr = e >> 5, rc = e & 31;
    float s = bias[n0 + rc];
#pragma unroll
    for (int w = 0; w < 8; ++w) s += red[w][rr][rc];
    dst[(size_t)rr * ld + n0 + rc] = f2bf(tanhf(s));
  }
}

__device__ __forceinline__ void reduce_f32(const float (*red)[128][32], const float* bias,
                                           float* dst, int n0, int tid, int ld) {
#pragma unroll
  for (int i = 0; i < 8; ++i) {
    int e = i * 512 + tid, rr = e >> 5, rc = e & 31;
    float s = bias[n0 + rc];
#pragma unroll
    for (int w = 0; w < 8; ++w) s += red[w][rr][rc];
    dst[(size_t)rr * ld + n0 + rc] = s;
  }
}

__global__ __launch_bounds__(512, 1) void rnn_main(
    const float* __restrict__ x,
    const u16* __restrict__ W1T, const u16* __restrict__ W2T, const u16* __restrict__ WoT,
    const float* __restrict__ b1, const float* __restrict__ b2, const float* __restrict__ bo,
    u16* __restrict__ h1ring, u16* __restrict__ h2ring,
    float* __restrict__ out, int* __restrict__ bar)
{
  __shared__ float red[8][128][32];     // 128 KB
  const int tid = threadIdx.x;
  const int kw = tid >> 6, lane = tid & 63;
  const int r16 = lane & 15, kg = lane >> 4;
  const int bid = blockIdx.x;
  int* flags = bar;                     // flags[b*16]
  int* prog  = bar + NBLK * 16;         // prog[g*16], g = 0(G1),1(G2),2(G3)

  if (bid < NB1) {
    // ================= G1: h1[k] = tanh([x_k | h1[k-1]] @ W1 + b1) =================
    const int n0 = bid * 32;
    bf16x8 Br[8][2];                    // wave kw's K-slice [kw*256, +256)
#pragma unroll
    for (int ks = 0; ks < 8; ++ks)
#pragma unroll
      for (int nf = 0; nf < 2; ++nf)
        Br[ks][nf] = *(const bf16x8*)(W1T + (size_t)(n0 + nf * 16 + r16) * K1
                                      + kw * 256 + ks * 32 + kg * 8);
    for (int k = 0; k < STEPS; ++k) {
      if (tid == 0) {
        wait_ge(&prog[0], k);           // all h1[k-1] written
        wait_ge(&prog[16], k - 3);      // ring back-pressure vs G2
      }
      __syncthreads();
      f32x4 acc[8][2] = {};
      if (kw < 2) {
        const float* xp[8];
#pragma unroll
        for (int mf = 0; mf < 8; ++mf)
          xp[mf] = x + (size_t)k * BATCH * INSZ + (size_t)(mf * 16 + r16) * INSZ
                   + kw * 256 + kg * 8;
        kloop_x(xp, Br, acc);
      } else {
        const u16* rp[8];
        const u16* base = h1ring + (size_t)((k + RING - 1) & (RING - 1)) * BATCH * H1SZ
                          + (kw - 2) * 256 + kg * 8;
#pragma unroll
        for (int mf = 0; mf < 8; ++mf) rp[mf] = base + (size_t)(mf * 16 + r16) * H1SZ;
        kloop_sc1<8>(rp, Br, acc);
      }
      store_red8(red, kw, kg, r16, acc);
      __syncthreads();
      reduce_tanh_bf16(red, b1, h1ring + (size_t)(k & (RING - 1)) * BATCH * H1SZ, n0, tid, H1SZ);
      __syncthreads();                  // drains vmcnt -> stores in L2
      if (tid == 0) relstore(&flags[bid * 16], k + 1);   // wbl2 + flag
      if (bid == 0) {
        if (tid < NB1) wait_ge(&flags[tid * 16], k + 1);
        __syncthreads();
        if (tid == 0) sysstore(&prog[0], k + 1);
      }
    }
  } else if (bid < NB1 + NB2) {
    // ================= G2: h2[j] = tanh([h1[j] | h2[j-1]] @ W2 + b2) =================
    const int n0 = (bid - NB1) * 32;
    bf16x8 Br[12][2];                   // wave kw's K-slice [kw*384, +384)
#pragma unroll
    for (int ks = 0; ks < 12; ++ks)
#pragma unroll
      for (int nf = 0; nf < 2; ++nf)
        Br[ks][nf] = *(const bf16x8*)(W2T + (size_t)(n0 + nf * 16 + r16) * K2
                                      + kw * 384 + ks * 32 + kg * 8);
    for (int j = 0; j < STEPS; ++j) {
      if (tid == 0) {
        wait_ge(&prog[16], j);          // all h2[j-1] written
        wait_ge(&prog[0], j + 1);       // h1[j] ready
        wait_ge(&prog[32], j - 3);      // ring back-pressure vs G3
      }
      __syncthreads();
      const u16* rp[8];
      const u16* base = (kw < 4)
        ? h1ring + (size_t)(j & (RING - 1)) * BATCH * H1SZ + kw * 384 + kg * 8
        : h2ring + (size_t)((j + RING - 1) & (RING - 1)) * BATCH * H2SZ + (kw - 4) * 384 + kg * 8;
#pragma unroll
      for (int mf = 0; mf < 8; ++mf) rp[mf] = base + (size_t)(mf * 16 + r16) * 1536;
      f32x4 acc[8][2] = {};
      kloop_sc1<12>(rp, Br, acc);
      store_red8(red, kw, kg, r16, acc);
      __syncthreads();
      reduce_tanh_bf16(red, b2, h2ring + (size_t)(j & (RING - 1)) * BATCH * H2SZ, n0, tid, H2SZ);
      __syncthreads();
      if (tid == 0) relstore(&flags[bid * 16], j + 1);
      if (bid == NB1) {
        if (tid < NB2) wait_ge(&flags[(NB1 + tid) * 16], j + 1);
        __syncthreads();
        if (tid == 0) sysstore(&prog[16], j + 1);
      }
    }
  } else {
    // ================= G3: out[j+1] = h2[j] @ Wo + bo =================
    const int n0 = (bid - NB1 - NB2) * 32;
    bf16x8 Br[6][2];                    // wave kw's K-slice [kw*192, +192)
#pragma unroll
    for (int ks = 0; ks < 6; ++ks)
#pragma unroll
      for (int nf = 0; nf < 2; ++nf)
        Br[ks][nf] = *(const bf16x8*)(WoT + (size_t)(n0 + nf * 16 + r16) * H2SZ
                                      + kw * 192 + ks * 32 + kg * 8);
    for (int j = 0; j < STEPS; ++j) {
      if (tid == 0) wait_ge(&prog[16], j + 1);   // h2[j] ready
      __syncthreads();
      const u16* rp[8];
      const u16* base = h2ring + (size_t)(j & (RING - 1)) * BATCH * H2SZ + kw * 192 + kg * 8;
#pragma unroll
      for (int mf = 0; mf < 8; ++mf) rp[mf] = base + (size_t)(mf * 16 + r16) * H2SZ;
      f32x4 acc[8][2] = {};
      kloop_sc1<6>(rp, Br, acc);
      store_red8(red, kw, kg, r16, acc);
      __syncthreads();
      reduce_f32(red, bo, out + (size_t)(j + 1) * BATCH * NOUT, n0, tid, NOUT);
      __syncthreads();                  // reads of h2[j] + out stores done
      if (tid == 0) sysstore(&flags[bid * 16], j + 1);   // back-pressure only
      if (bid == NB1 + NB2) {
        if (tid < NB3) wait_ge(&flags[(NB1 + NB2 + tid) * 16], j + 1);
        __syncthreads();
        if (tid == 0) sysstore(&prog[32], j + 1);
      }
    }
  }
}

// LDS-tiled transpose + fp32->bf16:  dst[n*K + k] = bf16(src[k*N + n])
__global__ void transpose_cvt(const float* __restrict__ src, u16* __restrict__ dst, int K, int N) {
  __shared__ u16 tile[32][33];
  int kb = blockIdx.x * 32, nb = blockIdx.y * 32;
  int tx = threadIdx.x & 31, ty = threadIdx.x >> 5;   // 32 x 8
  for (int i = ty; i < 32; i += 8)
    tile[i][tx] = f2bf(src[(size_t)(kb + i) * N + nb + tx]);
  __syncthreads();
  for (int i = ty; i < 32; i += 8)
    dst[(size_t)(nb + i) * K + kb + tx] = tile[tx][i];
}

extern "C" void kernel_launch(void* const* d_in, const int* in_sizes, int n_in,
                              void* d_out, int out_size, void* d_ws, size_t ws_size,
                              hipStream_t stream) {
  const float* x  = (const float*)d_in[0];
  const float* W1 = (const float*)d_in[1];
  const float* b1 = (const float*)d_in[2];
  const float* W2 = (const float*)d_in[3];
  const float* b2 = (const float*)d_in[4];
  const float* Wo = (const float*)d_in[5];
  const float* bo = (const float*)d_in[6];
  float* out = (float*)d_out;
  char*  ws  = (char*)d_ws;

  // ws layout (bytes)
  u16* W1T    = (u16*)(ws);                 // 2048*1536*2 = 6291456
  u16* W2T    = (u16*)(ws + 6291456);       // 3072*1536*2 = 9437184
  u16* WoT    = (u16*)(ws + 15728640);      // 1536* 512*2 = 1572864
  u16* h1ring = (u16*)(ws + 17301504);      // RING*128*1536*2 = 1572864
  u16* h2ring = (u16*)(ws + 18874368);      // 1572864
  int* bar    = (int*)(ws + 20447232);      // flags[112*16] + prog[3*16]

  // zero rings + sync state (deterministic each call); zero out row 0 (delay slot)
  hipMemsetAsync(ws + 17301504, 0, 1572864 * 2 + 8192, stream);
  hipMemsetAsync(d_out, 0, (size_t)BATCH * NOUT * sizeof(float), stream);

  transpose_cvt<<<dim3(K1 / 32, H1SZ / 32), 256, 0, stream>>>(W1, W1T, K1, H1SZ);
  transpose_cvt<<<dim3(K2 / 32, H1SZ / 32), 256, 0, stream>>>(W2, W2T, K2, H1SZ);
  transpose_cvt<<<dim3(H2SZ / 32, NOUT / 32), 256, 0, stream>>>(Wo, WoT, H2SZ, NOUT);

  rnn_main<<<NBLK, 512, 0, stream>>>(x, W1T, W2T, WoT, b1, b2, bo, h1ring, h2ring, out, bar);
}

// Round 6
// 3488.523 us; speedup vs baseline: 3.6058x; 2.0723x over previous
//
#include <hip/hip_runtime.h>
#include <math.h>

#define STEPS 256
#define BATCH 128
#define HALF_M 64
#define INSZ  512
#define H1SZ  1536
#define H2SZ  1536
#define NOUT  512
#define K1    2048   // INSZ + H1SZ
#define K2    3072   // H1SZ + H2SZ
#define NC1   48     // G1 col-blocks per half (32 cols each)
#define NC2   48
#define NC3   16
#define NBLK  224    // 2 halves * (48+48+16)

typedef short bf16x8 __attribute__((ext_vector_type(8)));
typedef float f32x4  __attribute__((ext_vector_type(4)));
typedef unsigned short u16;

__device__ __forceinline__ f32x4 mfma16(bf16x8 a, bf16x8 b, f32x4 c) {
  return __builtin_amdgcn_mfma_f32_16x16x32_bf16(a, b, c, 0, 0, 0);
}

__device__ __forceinline__ u16 f2bf(float f) {
  unsigned u = __builtin_bit_cast(unsigned, f);
  u += 0x7fffu + ((u >> 16) & 1u);
  return (u16)(u >> 16);
}

// 8 fp32 -> bf16x8 (RTNE) via packed cvt (register-only asm)
__device__ __forceinline__ bf16x8 cvt8(const float* p) {
  f32x4 lo = *(const f32x4*)p;
  f32x4 hi = *(const f32x4*)(p + 4);
  union { unsigned u[4]; bf16x8 v; } r;
  asm("v_cvt_pk_bf16_f32 %0, %1, %2" : "=v"(r.u[0]) : "v"(lo[0]), "v"(lo[1]));
  asm("v_cvt_pk_bf16_f32 %0, %1, %2" : "=v"(r.u[1]) : "v"(lo[2]), "v"(lo[3]));
  asm("v_cvt_pk_bf16_f32 %0, %1, %2" : "=v"(r.u[2]) : "v"(hi[0]), "v"(hi[1]));
  asm("v_cvt_pk_bf16_f32 %0, %1, %2" : "=v"(r.u[3]) : "v"(hi[2]), "v"(hi[3]));
  return r.v;
}

// ---- sealed async-load region primitives: ALL carry "memory" clobbers so no
// compiler memory op can cross into/out of the counted-vmcnt region. ----
#define LOAD_SC_OFS(dst, ptr, ofs) \
  asm volatile("global_load_dwordx4 %0, %1, off offset:%2 sc0 sc1" \
               : "=v"(dst) : "v"(ptr), "i"(ofs) : "memory")
#define STORE_SC(ptr, val) \
  asm volatile("global_store_dwordx4 %0, %1, off sc0 sc1" :: "v"(ptr), "v"(val) : "memory")
#define WAITV(n) asm volatile("s_waitcnt vmcnt(" #n ")" ::: "memory")
// pin a 4-VGPR value: opaque to remat, forces register residency
#define PIN4(v) asm volatile("" : "+v"(v))

__device__ __forceinline__ void wait_flag(const int* p, int v) {
  while (__hip_atomic_load(p, __ATOMIC_RELAXED, __HIP_MEMORY_SCOPE_SYSTEM) < v)
    __builtin_amdgcn_s_sleep(1);
}
__device__ __forceinline__ void set_flag(int* p, int v) {
  __hip_atomic_store(p, v, __ATOMIC_RELAXED, __HIP_MEMORY_SCOPE_SYSTEM);
}

// Depth-8 pipelined sc0sc1 K-loop, prefetch-after-consume, exact FIFO vmcnt.
// Entry WAITV(0) guarantees count starts at zero. base includes this wave's
// K-byte offset + kg*16B; rows stride 1536 bf16.
template<int NKS>
__device__ __forceinline__ void kloop_sc(const u16* base, const bf16x8 (*Br)[2],
                                         f32x4 (*acc)[2], int r16) {
  const u16* rp[4];
#pragma unroll
  for (int mf = 0; mf < 4; ++mf) rp[mf] = base + (size_t)(mf * 16 + r16) * 1536;
  bf16x8 A[8][4];
  WAITV(0);                                   // region entry: count = 0
  constexpr int D = (NKS < 8) ? NKS : 8;
#pragma unroll
  for (int d = 0; d < D; ++d)
#pragma unroll
    for (int mf = 0; mf < 4; ++mf)
      LOAD_SC_OFS(A[d][mf], rp[mf], d * 64);
#pragma unroll
  for (int ks = 0; ks < NKS; ++ks) {
    const int rem = (NKS - 1 - ks) < 7 ? (NKS - 1 - ks) : 7;  // compile-time after unroll
    if (rem == 7)      WAITV(28);
    else if (rem == 6) WAITV(24);
    else if (rem == 5) WAITV(20);
    else if (rem == 4) WAITV(16);
    else if (rem == 3) WAITV(12);
    else if (rem == 2) WAITV(8);
    else if (rem == 1) WAITV(4);
    else               WAITV(0);
    __builtin_amdgcn_sched_barrier(0);
#pragma unroll
    for (int mf = 0; mf < 4; ++mf) {
      acc[mf][0] = mfma16(A[ks & 7][mf], Br[ks][0], acc[mf][0]);
      acc[mf][1] = mfma16(A[ks & 7][mf], Br[ks][1], acc[mf][1]);
    }
    if (ks + 8 < NKS) {                       // refill the slot just consumed
#pragma unroll
      for (int mf = 0; mf < 4; ++mf)
        LOAD_SC_OFS(A[ks & 7][mf], rp[mf], (ks + 8) * 64);
    }
  }
}

// x path: cached fp32 compiler loads + cvt (runs BEFORE the sealed region)
__device__ __forceinline__ void kloop_x4(const float* xb, const bf16x8 (*Br)[2],
                                         f32x4 (*acc)[2], int r16) {
#pragma unroll
  for (int ks = 0; ks < 4; ++ks)
#pragma unroll
    for (int mf = 0; mf < 4; ++mf) {
      bf16x8 a = cvt8(xb + (size_t)(mf * 16 + r16) * INSZ + ks * 32);
      acc[mf][0] = mfma16(a, Br[ks][0], acc[mf][0]);
      acc[mf][1] = mfma16(a, Br[ks][1], acc[mf][1]);
    }
}

__device__ __forceinline__ void store_red(float (*red)[64][36], int kw, int kg, int r16,
                                          const f32x4 (*acc)[2]) {
#pragma unroll
  for (int mf = 0; mf < 4; ++mf)
#pragma unroll
    for (int nf = 0; nf < 2; ++nf)
#pragma unroll
      for (int r = 0; r < 4; ++r)
        red[kw][mf * 16 + kg * 4 + r][nf * 16 + r16] = acc[mf][nf][r];
}

// sum 4 waves + bias, tanh, pack, sc-store bf16x8
__device__ __forceinline__ void reduce_tanh_sc(const float (*red)[64][36], const float* bias,
                                               u16* dstbase, int n0, int tid) {
  const int row = tid >> 2, c0 = (tid & 3) * 8;
  f32x4 s0 = *(const f32x4*)(bias + n0 + c0);
  f32x4 s1 = *(const f32x4*)(bias + n0 + c0 + 4);
#pragma unroll
  for (int w = 0; w < 4; ++w) {
    s0 += *(const f32x4*)&red[w][row][c0];
    s1 += *(const f32x4*)&red[w][row][c0 + 4];
  }
  float t[8];
#pragma unroll
  for (int j = 0; j < 4; ++j) t[j] = tanhf(s0[j]);
#pragma unroll
  for (int j = 0; j < 4; ++j) t[4 + j] = tanhf(s1[j]);
  union { unsigned u[4]; bf16x8 v; } pk;
  asm("v_cvt_pk_bf16_f32 %0, %1, %2" : "=v"(pk.u[0]) : "v"(t[0]), "v"(t[1]));
  asm("v_cvt_pk_bf16_f32 %0, %1, %2" : "=v"(pk.u[1]) : "v"(t[2]), "v"(t[3]));
  asm("v_cvt_pk_bf16_f32 %0, %1, %2" : "=v"(pk.u[2]) : "v"(t[4]), "v"(t[5]));
  asm("v_cvt_pk_bf16_f32 %0, %1, %2" : "=v"(pk.u[3]) : "v"(t[6]), "v"(t[7]));
  u16* dst = dstbase + (size_t)row * 1536 + n0 + c0;
  STORE_SC(dst, pk.v);
}

__global__ __launch_bounds__(256, 1) void rnn_main(
    const float* __restrict__ x,
    const u16* __restrict__ W1T, const u16* __restrict__ W2T, const u16* __restrict__ WoT,
    const float* __restrict__ b1, const float* __restrict__ b2, const float* __restrict__ bo,
    u16* __restrict__ h1ring, u16* __restrict__ h2ring,
    float* __restrict__ out, int* __restrict__ bar)
{
  __shared__ float red[4][64][36];
  const int tid = threadIdx.x;
  const int kw = tid >> 6, lane = tid & 63;
  const int r16 = lane & 15, kg = lane >> 4;
  const int bid = blockIdx.x;

  int grp, half, col;
  if (bid < 2 * NC1)              { grp = 0; half = bid / NC1;         col = bid % NC1; }
  else if (bid < 2 * (NC1 + NC2)) { grp = 1; half = (bid - 96) / NC2;  col = (bid - 96) % NC2; }
  else                            { grp = 2; half = (bid - 192) / NC3; col = (bid - 192) % NC3; }
  const int n0 = col * 32;
  int* f1 = bar + (half * NC1) * 16;
  int* f2 = bar + (96 + half * NC2) * 16;
  int* f3 = bar + (192 + half * NC3) * 16;

  u16* h1base = h1ring + (size_t)half * 4 * HALF_M * H1SZ;
  u16* h2base = h2ring + (size_t)half * 4 * HALF_M * H2SZ;

  if (grp == 0) {
    // ===== G1: h1[k] = tanh([x_k | h1[k-1]] @ W1 + b1) =====
    bf16x8 BrX[4][2], Brh[12][2];
#pragma unroll
    for (int ks = 0; ks < 4; ++ks)
#pragma unroll
      for (int nf = 0; nf < 2; ++nf)
        BrX[ks][nf] = *(const bf16x8*)(W1T + (size_t)(n0 + nf * 16 + r16) * K1
                                       + kw * 128 + ks * 32 + kg * 8);
#pragma unroll
    for (int ks = 0; ks < 12; ++ks)
#pragma unroll
      for (int nf = 0; nf < 2; ++nf)
        Brh[ks][nf] = *(const bf16x8*)(W1T + (size_t)(n0 + nf * 16 + r16) * K1
                                       + 512 + kw * 384 + ks * 32 + kg * 8);
#pragma unroll
    for (int ks = 0; ks < 4; ++ks) { PIN4(BrX[ks][0]); PIN4(BrX[ks][1]); }
#pragma unroll
    for (int ks = 0; ks < 12; ++ks) { PIN4(Brh[ks][0]); PIN4(Brh[ks][1]); }

    for (int k = 0; k < STEPS; ++k) {
      if (tid < NC1) wait_flag(&f1[tid * 16], k);                                    // h1[k-1]
      else if (tid >= 64 && tid < 64 + NC2) wait_flag(&f2[(tid - 64) * 16], k - 3);  // ring free
      __syncthreads();
      f32x4 acc[4][2] = {};
      const float* xb = x + ((size_t)k * BATCH + half * HALF_M) * INSZ + kw * 128 + kg * 8;
      kloop_x4(xb, BrX, acc, r16);
      const u16* hb = h1base + (size_t)((k + 3) & 3) * HALF_M * H1SZ + kw * 384 + kg * 8;
      kloop_sc<12>(hb, Brh, acc, r16);
      store_red(red, kw, kg, r16, acc);
      __syncthreads();
      reduce_tanh_sc(red, b1, h1base + (size_t)(k & 3) * HALF_M * H1SZ, n0, tid);
      WAITV(0);                       // own sc-stores complete
      __syncthreads();                // all threads' stores complete
      if (tid == 0) set_flag(&f1[col * 16], k + 1);
    }
  } else if (grp == 1) {
    // ===== G2: h2[j] = tanh([h1[j] | h2[j-1]] @ W2 + b2) =====
    bf16x8 Br[24][2];
#pragma unroll
    for (int ks = 0; ks < 24; ++ks)
#pragma unroll
      for (int nf = 0; nf < 2; ++nf)
        Br[ks][nf] = *(const bf16x8*)(W2T + (size_t)(n0 + nf * 16 + r16) * K2
                                      + kw * 768 + ks * 32 + kg * 8);
#pragma unroll
    for (int ks = 0; ks < 24; ++ks) { PIN4(Br[ks][0]); PIN4(Br[ks][1]); }

    for (int j = 0; j < STEPS; ++j) {
      if (tid < NC1) wait_flag(&f1[tid * 16], j + 1);                                   // h1[j]
      else if (tid >= 64 && tid < 64 + NC2) wait_flag(&f2[(tid - 64) * 16], j);         // h2[j-1]
      else if (tid >= 128 && tid < 128 + NC3) wait_flag(&f3[(tid - 128) * 16], j - 3);  // ring
      __syncthreads();
      const u16* hb = (kw < 2)
        ? h1base + (size_t)(j & 3) * HALF_M * H1SZ + kw * 768 + kg * 8
        : h2base + (size_t)((j + 3) & 3) * HALF_M * H2SZ + (kw - 2) * 768 + kg * 8;
      f32x4 acc[4][2] = {};
      kloop_sc<24>(hb, Br, acc, r16);
      store_red(red, kw, kg, r16, acc);
      __syncthreads();
      reduce_tanh_sc(red, b2, h2base + (size_t)(j & 3) * HALF_M * H2SZ, n0, tid);
      WAITV(0);
      __syncthreads();
      if (tid == 0) set_flag(&f2[col * 16], j + 1);
    }
  } else {
    // ===== G3: out[j+1] = h2[j] @ Wo + bo =====
    bf16x8 Br[12][2];
#pragma unroll
    for (int ks = 0; ks < 12; ++ks)
#pragma unroll
      for (int nf = 0; nf < 2; ++nf)
        Br[ks][nf] = *(const bf16x8*)(WoT + (size_t)(n0 + nf * 16 + r16) * H2SZ
                                      + kw * 384 + ks * 32 + kg * 8);
#pragma unroll
    for (int ks = 0; ks < 12; ++ks) { PIN4(Br[ks][0]); PIN4(Br[ks][1]); }

    for (int j = 0; j < STEPS; ++j) {
      if (tid < NC2) wait_flag(&f2[tid * 16], j + 1);                                // h2[j]
      __syncthreads();
      const u16* hb = h2base + (size_t)(j & 3) * HALF_M * H2SZ + kw * 384 + kg * 8;
      f32x4 acc[4][2] = {};
      kloop_sc<12>(hb, Br, acc, r16);
      store_red(red, kw, kg, r16, acc);
      __syncthreads();
      {
        const int row = tid >> 2, c0 = (tid & 3) * 8;
        f32x4 s0 = *(const f32x4*)(bo + n0 + c0);
        f32x4 s1 = *(const f32x4*)(bo + n0 + c0 + 4);
#pragma unroll
        for (int w = 0; w < 4; ++w) {
          s0 += *(const f32x4*)&red[w][row][c0];
          s1 += *(const f32x4*)&red[w][row][c0 + 4];
        }
        float* dst = out + ((size_t)(j + 1) * BATCH + half * HALF_M + row) * NOUT + n0 + c0;
        *(f32x4*)dst = s0;
        *(f32x4*)(dst + 4) = s1;
      }
      __syncthreads();                // h2 reads retired before signaling consumption
      if (tid == 0) set_flag(&f3[col * 16], j + 1);
    }
  }
}

// LDS-tiled transpose + fp32->bf16:  dst[n*K + k] = bf16(src[k*N + n])
__global__ void transpose_cvt(const float* __restrict__ src, u16* __restrict__ dst, int K, int N) {
  __shared__ u16 tile[32][33];
  int kb = blockIdx.x * 32, nb = blockIdx.y * 32;
  int tx = threadIdx.x & 31, ty = threadIdx.x >> 5;
  for (int i = ty; i < 32; i += 8)
    tile[i][tx] = f2bf(src[(size_t)(kb + i) * N + nb + tx]);
  __syncthreads();
  for (int i = ty; i < 32; i += 8)
    dst[(size_t)(nb + i) * K + kb + tx] = tile[tx][i];
}

extern "C" void kernel_launch(void* const* d_in, const int* in_sizes, int n_in,
                              void* d_out, int out_size, void* d_ws, size_t ws_size,
                              hipStream_t stream) {
  const float* x  = (const float*)d_in[0];
  const float* W1 = (const float*)d_in[1];
  const float* b1 = (const float*)d_in[2];
  const float* W2 = (const float*)d_in[3];
  const float* b2 = (const float*)d_in[4];
  const float* Wo = (const float*)d_in[5];
  const float* bo = (const float*)d_in[6];
  float* out = (float*)d_out;
  char*  ws  = (char*)d_ws;

  u16* W1T    = (u16*)(ws);                 // 2048*1536*2 = 6291456
  u16* W2T    = (u16*)(ws + 6291456);       // 3072*1536*2 = 9437184
  u16* WoT    = (u16*)(ws + 15728640);      // 1536* 512*2 = 1572864
  u16* h1ring = (u16*)(ws + 17301504);      // 2 halves * 4 slots * 64*1536*2 = 1572864
  u16* h2ring = (u16*)(ws + 18874368);      // 1572864
  int* bar    = (int*)(ws + 20447232);      // 224 flags * 64B = 14336

  hipMemsetAsync(ws + 17301504, 0, 1572864 * 2 + 14336, stream);
  hipMemsetAsync(d_out, 0, (size_t)BATCH * NOUT * sizeof(float), stream);

  transpose_cvt<<<dim3(K1 / 32, H1SZ / 32), 256, 0, stream>>>(W1, W1T, K1, H1SZ);
  transpose_cvt<<<dim3(K2 / 32, H1SZ / 32), 256, 0, stream>>>(W2, W2T, K2, H1SZ);
  transpose_cvt<<<dim3(H2SZ / 32, NOUT / 32), 256, 0, stream>>>(Wo, WoT, H2SZ, NOUT);

  rnn_main<<<NBLK, 256, 0, stream>>>(x, W1T, W2T, WoT, b1, b2, bo, h1ring, h2ring, out, bar);
}